// Round 5
// baseline (1082.748 us; speedup 1.0000x reference)
//
#include <hip/hip_runtime.h>

#define B_   256
#define NIN_ 512
#define T_   256
#define H1_  512
#define H2_  512
#define OUT_ 128

typedef __attribute__((ext_vector_type(4))) int i32x4;
typedef __attribute__((address_space(1))) const unsigned int* gl_cu;
typedef __attribute__((address_space(3))) unsigned int* ls_u;

// ---------------------------------------------------------------------------
// Per-tensor absmax -> scale = max|W|/127.  One block per tensor.
// ---------------------------------------------------------------------------
__global__ void absmax_k(const float* __restrict__ W1, const float* __restrict__ W2,
                         const float* __restrict__ Wr, const float* __restrict__ W3,
                         float* __restrict__ scales) {
  const float* W; int n;
  switch (blockIdx.x) {
    case 0:  W = W1; n = H1_ * NIN_; break;
    case 1:  W = W2; n = H2_ * H1_;  break;
    case 2:  W = Wr; n = H2_ * H2_;  break;
    default: W = W3; n = OUT_ * H2_; break;
  }
  int tid = threadIdx.x;
  float m = 0.f;
  const float4* W4 = (const float4*)W;
  int n4 = n >> 2;
  for (int i = tid; i < n4; i += 256) {
    float4 v = W4[i];
    m = fmaxf(m, fmaxf(fmaxf(fabsf(v.x), fabsf(v.y)), fmaxf(fabsf(v.z), fabsf(v.w))));
  }
  __shared__ float red[256];
  red[tid] = m;
  __syncthreads();
  for (int s = 128; s > 0; s >>= 1) {
    if (tid < s) red[tid] = fmaxf(red[tid], red[tid + s]);
    __syncthreads();
  }
  if (tid == 0) scales[blockIdx.x] = red[0] / 127.0f;
}

// ---------------------------------------------------------------------------
// Fused quantization of all four weight tensors (one launch).
//  blocks 0..1023    : W1 -> fp32 q*s, transposed [NIN][H1]    (W1qT)
//  blocks 1024..2047 : W2 -> int8 q, row-major [H2][H1]        (W2i8)
//  blocks 2048..3071 : Wr -> int8 q, presyn-major [H2][H2]     (WrT, transposed)
//  blocks 3072..3327 : W3 -> int8 q, row-major [OUT][H2]       (W3i8)
// Same q integers as before; W2/W3 now stored as int8 for the i8-MFMA path
// (sums identical: spike(0/1) x q summed in i32 == 1.0 x q summed in f32).
// ---------------------------------------------------------------------------
__global__ void quant_all_k(const float* __restrict__ W1, const float* __restrict__ W2,
                            const float* __restrict__ Wr, const float* __restrict__ W3,
                            const float* __restrict__ scales,
                            float* __restrict__ W1qT, signed char* __restrict__ W2i8,
                            signed char* __restrict__ WrT, signed char* __restrict__ W3i8) {
  const int blk = blockIdx.x;
  if (blk < 1024) {
    int idx = blk * 256 + threadIdx.x;
    int h = idx & (H1_ - 1), i = idx >> 9;
    float s = scales[0];
    float q = rintf(W1[h * NIN_ + i] / s);
    q = fminf(fmaxf(q, -127.f), 127.f);
    W1qT[idx] = q * s;
  } else if (blk < 2048) {
    int idx = (blk - 1024) * 256 + threadIdx.x;
    float s = scales[1];
    float q = rintf(W2[idx] / s);
    q = fminf(fmaxf(q, -127.f), 127.f);
    W2i8[idx] = (signed char)q;
  } else if (blk < 3072) {
    int idx = (blk - 2048) * 256 + threadIdx.x;
    int r = idx >> 9, c = idx & (H2_ - 1);
    float s = scales[2];
    float q = rintf(Wr[idx] / s);
    q = fminf(fmaxf(q, -127.f), 127.f);
    WrT[(size_t)c * H2_ + r] = (signed char)q;
  } else {
    int idx = (blk - 3072) * 256 + threadIdx.x;
    float s = scales[3];
    float q = rintf(W3[idx] / s);
    q = fminf(fmaxf(q, -127.f), 127.f);
    W3i8[idx] = (signed char)q;
  }
}

// ---------------------------------------------------------------------------
// Phase A: cur1[t,b,h] = sum_i data[b,i,t] * W1qT[i,h].  fp32.
// ROUND-2 VERIFIED STRUCTURE (388 us): 128x128 tile, 512 threads (8 waves),
// per-thread 4x8, BK=16, double-buffered LDS via global_load_lds, plain
// __syncthreads.  Rounds 1/3/4 (bigger tile, zero-LDS, counted-vmcnt) all
// regressed -- this is the empirical optimum for the bit-exact fp32 chain.
// FMA order: per output element a single accumulator over k ascending
// 0..511 -> bit-identical cur1.  GOLDEN arithmetic preserved.
// ---------------------------------------------------------------------------
__global__ __launch_bounds__(512, 6) void gemm_cur1_k(const float* __restrict__ data,
                                                      const float* __restrict__ W1qT,
                                                      float* __restrict__ cur1) {
  const int b  = blockIdx.y;
  const int t0 = (blockIdx.x >> 2) << 7;
  const int h0 = (blockIdx.x & 3) << 7;
  const int tid = threadIdx.x;

  __shared__ float As[2][16][128];   // 16 KB
  __shared__ float Bs[2][16][128];   // 16 KB

  const int ty = tid >> 4, tx = tid & 15;   // ty 0..31, tx 0..15
  const int wv = tid >> 6;                  // 0..7
  const int ln = tid & 63;

  float acc[4][8];
#pragma unroll
  for (int i = 0; i < 4; i++)
#pragma unroll
    for (int j = 0; j < 8; j++) acc[i][j] = 0.f;

  const float* dbase = data + (size_t)b * NIN_ * T_;

  // Each wave stages 2 A-rows and 2 B-rows per phase (1 global_load_lds each:
  // 64 lanes x 16 B = 1024 B = 2 rows of 128 floats, linear LDS dest).
  auto issue = [&](int kb, int buf) {
    const int kr = (wv << 1) + (ln >> 5);
    const float* ga = dbase + (size_t)(kb + kr) * T_ + t0 + ((ln & 31) << 2);
    __builtin_amdgcn_global_load_lds((gl_cu)ga, (ls_u)&As[buf][wv << 1][0], 16, 0, 0);
    const float* gb = W1qT + (size_t)(kb + kr) * H1_ + h0 + ((ln & 31) << 2);
    __builtin_amdgcn_global_load_lds((gl_cu)gb, (ls_u)&Bs[buf][wv << 1][0], 16, 0, 0);
  };

  issue(0, 0);

  for (int p = 0; p < 32; p++) {
    const int cur = p & 1;
    __syncthreads();
    if (p < 31) issue((p + 1) << 4, cur ^ 1);
#pragma unroll
    for (int k = 0; k < 16; k++) {
      float4 A0 = *(const float4*)&As[cur][k][ty * 4];
      float4 B0 = *(const float4*)&Bs[cur][k][tx * 4];
      float4 B1 = *(const float4*)&Bs[cur][k][64 + tx * 4];
      float a[4] = {A0.x, A0.y, A0.z, A0.w};
      float w[8] = {B0.x, B0.y, B0.z, B0.w, B1.x, B1.y, B1.z, B1.w};
#pragma unroll
      for (int i = 0; i < 4; i++)
#pragma unroll
        for (int j = 0; j < 8; j++)
          acc[i][j] = fmaf(a[i], w[j], acc[i][j]);
    }
  }

#pragma unroll
  for (int i = 0; i < 4; i++) {
    int row = ty * 4 + i;
    float* op = cur1 + (size_t)(t0 + row) * (B_ * H1_) + (size_t)b * H1_ + h0;
    float4 cA = {acc[i][0], acc[i][1], acc[i][2], acc[i][3]};
    float4 cB = {acc[i][4], acc[i][5], acc[i][6], acc[i][7]};
    *(float4*)(op + tx * 4)      = cA;
    *(float4*)(op + 64 + tx * 4) = cB;
  }
}

// ---------------------------------------------------------------------------
// scan1: parallel per-neuron layer-1 LIF scan (per-column op order unchanged).
// Round-10: vectorized -- each thread owns 4 consecutive n, float4 loads /
// uchar4 stores (16 B/lane in, 4 B/lane out).  Per-column arithmetic chain
// identical to the scalar version -> bit-identical s1u.
// ---------------------------------------------------------------------------
__global__ __launch_bounds__(256) void scan1_k(const float* __restrict__ cur1,
                                               unsigned char* __restrict__ s1u,
                                               const float* __restrict__ beta1p,
                                               const float* __restrict__ th1p) {
  const int n0 = (blockIdx.x * 256 + threadIdx.x) << 2;
  const float b1 = fminf(fmaxf(beta1p[0], 0.f), 1.f);
  const float th1 = th1p[0];
  const size_t S = (size_t)B_ * H1_;
  float m0 = 0.f, m1 = 0.f, m2 = 0.f, m3 = 0.f;
#pragma unroll 2
  for (int t = 0; t < T_; t++) {
    float4 c = *(const float4*)(cur1 + (size_t)t * S + n0);
    uchar4 o;
    m0 = b1 * m0 + c.x; bool s0 = m0 - th1 > 0.f; if (s0) m0 = 0.f; o.x = s0;
    m1 = b1 * m1 + c.y; bool s1 = m1 - th1 > 0.f; if (s1) m1 = 0.f; o.y = s1;
    m2 = b1 * m2 + c.z; bool s2 = m2 - th1 > 0.f; if (s2) m2 = 0.f; o.z = s2;
    m3 = b1 * m3 + c.w; bool s3 = m3 - th1 > 0.f; if (s3) m3 = 0.f; o.w = s3;
    *(uchar4*)(s1u + (size_t)t * S + n0) = o;
  }
}

// ---------------------------------------------------------------------------
// Spike GEMM via i8 MFMA (exact integer sums, i32 accumulate).
// Round-10: replaces the bf16 path.  A = spike bytes (0/1 int8) -- used RAW,
// no conversion VALU at all.  B = int8 quantized weights.  K=64 per MFMA
// (2x the bf16 K=32), so 128 MFMA/wave instead of 256, and LDS traffic
// halves.  Byte geometry of fragments is IDENTICAL to the verified bf16
// kernel: per MFMA a lane reads 16 B of its row at offset quad*16 within
// the 64-byte k-window (bf16: quad*8 shorts = same bytes).  i32 sums equal
// the old f32 sums exactly (integers << 2^24) -> identical C floats.
// ---------------------------------------------------------------------------
__global__ __launch_bounds__(256) void gemm_spk_k(const unsigned char* __restrict__ A8,
                                                  const signed char* __restrict__ Bw,
                                                  float* __restrict__ C, int N) {
  __shared__ __align__(16) signed char As[128 * 80];   // 10 KB, row stride 80
  __shared__ __align__(16) signed char Bs[128 * 80];   // 10 KB
  const int tid = threadIdx.x;
  const int m0 = blockIdx.y << 7;
  const int n0 = blockIdx.x << 7;
  const int lane = tid & 63, wave = tid >> 6;
  const int quad = lane >> 4, lm = lane & 15;
  const int wm = wave << 5;

  i32x4 acc[2][8];
#pragma unroll
  for (int s = 0; s < 2; s++)
#pragma unroll
    for (int n = 0; n < 8; n++) acc[s][n] = (i32x4){0, 0, 0, 0};

  const int row = tid >> 2;            // 0..63 (+64 on second pass)
  const int offB = (tid & 3) << 4;     // 0/16/32/48 within 64-byte k-window

  for (int kb = 0; kb < 512; kb += 64) {
    uint4 av[2], bv[2];
#pragma unroll
    for (int i = 0; i < 2; i++) {
      const int r = row + (i << 6);
      av[i] = *(const uint4*)(A8 + (size_t)(m0 + r) * 512 + kb + offB);
      bv[i] = *(const uint4*)(Bw + (size_t)(n0 + r) * 512 + kb + offB);
    }
    __syncthreads();
#pragma unroll
    for (int i = 0; i < 2; i++) {
      const int r = row + (i << 6);
      *(uint4*)&As[r * 80 + offB] = av[i];
      *(uint4*)&Bs[r * 80 + offB] = bv[i];
    }
    __syncthreads();
    i32x4 a0 = *(const i32x4*)&As[(wm + lm) * 80 + (quad << 4)];
    i32x4 a1 = *(const i32x4*)&As[(wm + 16 + lm) * 80 + (quad << 4)];
    i32x4 bq[8];
#pragma unroll
    for (int n = 0; n < 8; n++)
      bq[n] = *(const i32x4*)&Bs[((n << 4) + lm) * 80 + (quad << 4)];
#pragma unroll
    for (int n = 0; n < 8; n++) {
      acc[0][n] = __builtin_amdgcn_mfma_i32_16x16x64_i8(a0, bq[n], acc[0][n], 0, 0, 0);
      acc[1][n] = __builtin_amdgcn_mfma_i32_16x16x64_i8(a1, bq[n], acc[1][n], 0, 0, 0);
    }
    __syncthreads();
  }

#pragma unroll
  for (int s = 0; s < 2; s++)
#pragma unroll
    for (int n = 0; n < 8; n++) {
      int orow = m0 + wm + (s << 4) + quad * 4;
      int col = n0 + (n << 4) + lm;
#pragma unroll
      for (int r = 0; r < 4; r++)
        C[(size_t)(orow + r) * N + col] = (float)acc[s][n][r];
    }
}

// ---------------------------------------------------------------------------
__device__ __forceinline__ void unp_add(unsigned w, int* a) {
  int iw = (int)w;
  a[0] += (iw << 24) >> 24;
  a[1] += (iw << 16) >> 24;
  a[2] += (iw << 8) >> 24;
  a[3] += iw >> 24;
}

// ---------------------------------------------------------------------------
// Sequential recurrent layer.  One block per batch row, 1024 threads.
// ---------------------------------------------------------------------------
__global__ __launch_bounds__(1024) void recurrent_k(
    const float* __restrict__ cur2a,       // [T*B, H2]
    const signed char* __restrict__ WrT,   // [H2][H2] presyn-major
    unsigned char* __restrict__ sru,       // [T*B, H2]
    const float* __restrict__ scales,
    const float* __restrict__ betarp, const float* __restrict__ thrp) {
  const int b = blockIdx.x;
  const int tid = threadIdx.x;
  const float s2sc = scales[1];
  const float srsc = scales[2];
  const float br = fminf(fmaxf(betarp[0], 0.f), 1.f);
  const float thr = thrp[0];

  const unsigned* WrT4 = (const unsigned*)WrT;   // [H2][128] dwords

  __shared__ unsigned WrL[256 * 128];   // 128 KB: presyn rows 0..255
  __shared__ int red[8][H2_];           // 16 KB
  __shared__ int lstLo[2][256];         // 2 KB
  __shared__ int lstHi[2][256];         // 2 KB
  __shared__ int ncLo[2], ncHi[2];

  {
    const uint4* src = (const uint4*)WrT4;
    uint4* dst = (uint4*)WrL;
    for (int i = tid; i < 8192; i += 1024) dst[i] = src[i];
  }
  if (tid < 2) { ncLo[tid] = 0; ncHi[tid] = 0; }
  __syncthreads();

  float mr = 0.f, sr_own = 0.f;
  const int g = tid >> 7;        // 0..7
  const int c = tid & 127;       // dword column

  for (int t = 0; t < T_; t++) {
    const int old = t & 1, nxt = old ^ 1;
    float c2 = 0.f;
    if (tid < H2_) c2 = cur2a[((size_t)t * B_ + b) * H2_ + tid];
    if (tid == 1022) ncLo[nxt] = 0;
    if (tid == 1023) ncHi[nxt] = 0;
    const int nLo = ncLo[old];
    const int nHi = ncHi[old];
    const int* LLo = lstLo[old];
    const int* LHi = lstHi[old];

    int a4[4] = {0, 0, 0, 0};
    // ---- LDS-resident half (rows < 256) ----
    {
      int k = g;
      for (; k + 56 < nLo; k += 64) {
        int i0 = LLo[k],      i1 = LLo[k + 8],  i2 = LLo[k + 16], i3 = LLo[k + 24];
        int i4 = LLo[k + 32], i5 = LLo[k + 40], i6 = LLo[k + 48], i7 = LLo[k + 56];
        unsigned w0 = WrL[(i0 << 7) + c], w1 = WrL[(i1 << 7) + c];
        unsigned w2 = WrL[(i2 << 7) + c], w3 = WrL[(i3 << 7) + c];
        unsigned w4 = WrL[(i4 << 7) + c], w5 = WrL[(i5 << 7) + c];
        unsigned w6 = WrL[(i6 << 7) + c], w7 = WrL[(i7 << 7) + c];
        unp_add(w0, a4); unp_add(w1, a4); unp_add(w2, a4); unp_add(w3, a4);
        unp_add(w4, a4); unp_add(w5, a4); unp_add(w6, a4); unp_add(w7, a4);
      }
      for (; k + 24 < nLo; k += 32) {
        int i0 = LLo[k], i1 = LLo[k + 8], i2 = LLo[k + 16], i3 = LLo[k + 24];
        unsigned w0 = WrL[(i0 << 7) + c], w1 = WrL[(i1 << 7) + c];
        unsigned w2 = WrL[(i2 << 7) + c], w3 = WrL[(i3 << 7) + c];
        unp_add(w0, a4); unp_add(w1, a4); unp_add(w2, a4); unp_add(w3, a4);
      }
      for (; k < nLo; k += 8) unp_add(WrL[(LLo[k] << 7) + c], a4);
    }
    // ---- global half (rows >= 256) ----
    {
      int k = g;
      for (; k + 56 < nHi; k += 64) {
        int i0 = LHi[k],      i1 = LHi[k + 8],  i2 = LHi[k + 16], i3 = LHi[k + 24];
        int i4 = LHi[k + 32], i5 = LHi[k + 40], i6 = LHi[k + 48], i7 = LHi[k + 56];
        unsigned w0 = WrT4[(i0 << 7) + c], w1 = WrT4[(i1 << 7) + c];
        unsigned w2 = WrT4[(i2 << 7) + c], w3 = WrT4[(i3 << 7) + c];
        unsigned w4 = WrT4[(i4 << 7) + c], w5 = WrT4[(i5 << 7) + c];
        unsigned w6 = WrT4[(i6 << 7) + c], w7 = WrT4[(i7 << 7) + c];
        unp_add(w0, a4); unp_add(w1, a4); unp_add(w2, a4); unp_add(w3, a4);
        unp_add(w4, a4); unp_add(w5, a4); unp_add(w6, a4); unp_add(w7, a4);
      }
      for (; k + 24 < nHi; k += 32) {
        int i0 = LHi[k], i1 = LHi[k + 8], i2 = LHi[k + 16], i3 = LHi[k + 24];
        unsigned w0 = WrT4[(i0 << 7) + c], w1 = WrT4[(i1 << 7) + c];
        unsigned w2 = WrT4[(i2 << 7) + c], w3 = WrT4[(i3 << 7) + c];
        unp_add(w0, a4); unp_add(w1, a4); unp_add(w2, a4); unp_add(w3, a4);
      }
      for (; k < nHi; k += 8) unp_add(WrT4[(LHi[k] << 7) + c], a4);
    }
    *(int4*)&red[g][c << 2] = make_int4(a4[0], a4[1], a4[2], a4[3]);
    __syncthreads();                               // S1

    bool spike = false;
    if (tid < H2_) {
      int acc = red[0][tid] + red[1][tid] + red[2][tid] + red[3][tid]
              + red[4][tid] + red[5][tid] + red[6][tid] + red[7][tid];
      float h = s2sc * c2 + srsc * (float)acc;
      mr = (br * mr + h) * (1.f - sr_own);
      sr_own = (mr - thr > 0.f) ? 1.f : 0.f;
      sru[((size_t)t * B_ + b) * H2_ + tid] = (unsigned char)(sr_own != 0.f);
      spike = (sr_own != 0.f);
    }
    unsigned long long bm = __ballot(spike);
    if (bm != 0ull) {
      const int lane = tid & 63;
      const int ldr = (int)__ffsll((long long)bm) - 1;
      int* cnt = (tid < 256) ? &ncLo[nxt] : &ncHi[nxt];   // wave-uniform choice
      int* dst = (tid < 256) ? lstLo[nxt] : lstHi[nxt];
      int base = 0;
      if (lane == ldr) base = atomicAdd(cnt, (int)__popcll(bm));
      base = __shfl(base, ldr);
      if (spike)
        dst[base + (int)__popcll(bm & ((1ull << lane) - 1ull))] = tid;
    }
    __syncthreads();                               // S2
  }
}

// ---------------------------------------------------------------------------
// scan3: parallel layer-2 LIF scan over precomputed cur3 sums.
// ---------------------------------------------------------------------------
__global__ __launch_bounds__(256) void scan3_k(const float* __restrict__ cur3,
                                               float* __restrict__ out,
                                               const float* __restrict__ scales,
                                               const float* __restrict__ beta2p,
                                               const float* __restrict__ th2p) {
  const int n = blockIdx.x * 256 + threadIdx.x;
  const float s3sc = scales[3];
  const float b2 = fminf(fmaxf(beta2p[0], 0.f), 1.f);
  const float th2 = th2p[0];
  const size_t S = (size_t)B_ * OUT_;
  float m2 = 0.f;
  for (int t = 0; t < T_; t += 4) {
    float v0 = cur3[(size_t)t * S + n];
    float v1 = cur3[(size_t)(t + 1) * S + n];
    float v2 = cur3[(size_t)(t + 2) * S + n];
    float v3 = cur3[(size_t)(t + 3) * S + n];
    m2 = b2 * m2 + s3sc * v0; float p0 = (m2 - th2 > 0.f) ? 1.f : 0.f; m2 *= (1.f - p0);
    out[(size_t)t * S + n] = p0;
    m2 = b2 * m2 + s3sc * v1; float p1 = (m2 - th2 > 0.f) ? 1.f : 0.f; m2 *= (1.f - p1);
    out[(size_t)(t + 1) * S + n] = p1;
    m2 = b2 * m2 + s3sc * v2; float p2 = (m2 - th2 > 0.f) ? 1.f : 0.f; m2 *= (1.f - p2);
    out[(size_t)(t + 2) * S + n] = p2;
    m2 = b2 * m2 + s3sc * v3; float p3 = (m2 - th2 > 0.f) ? 1.f : 0.f; m2 *= (1.f - p3);
    out[(size_t)(t + 3) * S + n] = p3;
  }
}

// ---------------------------------------------------------------------------
extern "C" void kernel_launch(void* const* d_in, const int* in_sizes, int n_in,
                              void* d_out, int out_size, void* d_ws, size_t ws_size,
                              hipStream_t stream) {
  const float* data  = (const float*)d_in[0];
  const float* W1    = (const float*)d_in[1];
  const float* W2    = (const float*)d_in[2];
  const float* Wr    = (const float*)d_in[3];
  const float* W3    = (const float*)d_in[4];
  const float* beta1 = (const float*)d_in[5];
  const float* th1   = (const float*)d_in[6];
  const float* betar = (const float*)d_in[7];
  const float* thr   = (const float*)d_in[8];
  const float* beta2 = (const float*)d_in[9];
  const float* th2   = (const float*)d_in[10];

  char* ws = (char*)d_ws;
  float*         scales = (float*)ws;                                   // @0
  float*         W1qT   = (float*)(ws + 4096);                          // 1 MB [NIN][H1]
  signed char*   W2i8   = (signed char*)(ws + 4096 + 1048576);          // 256 KB [H2][H1]
  signed char*   W3i8   = (signed char*)(ws + 4096 + 1048576 + 524288); // 64 KB [OUT][H2]
  signed char*   WrT    = (signed char*)(ws + 4096 + 1048576 + 524288 + 131072); // 256 KB
  // region A (128 MB): cur1 -> cur2a -> cur3 (sequential lifetimes)
  float*         regA   = (float*)(ws + (size_t)4194304);
  // region B (64 MB): s1u + sru
  unsigned char* regB   = (unsigned char*)(ws + (size_t)4194304 + 134217728);

  float* cur1  = regA;
  float* cur2a = regA;
  float* cur3  = regA;
  unsigned char* s1u = regB;
  unsigned char* sru = regB + (size_t)33554432;

  hipLaunchKernelGGL(absmax_k, dim3(4), dim3(256), 0, stream, W1, W2, Wr, W3, scales);
  hipLaunchKernelGGL(quant_all_k, dim3(3328), dim3(256), 0, stream,
                     W1, W2, Wr, W3, scales, W1qT, W2i8, WrT, W3i8);

  hipLaunchKernelGGL(gemm_cur1_k, dim3(8, 256), dim3(512), 0, stream, data, W1qT, cur1);
  hipLaunchKernelGGL(scan1_k, dim3((B_ * H1_) / 1024), dim3(256), 0, stream, cur1, s1u, beta1, th1);
  hipLaunchKernelGGL(gemm_spk_k, dim3(4, 512), dim3(256), 0, stream, s1u, W2i8, cur2a, H2_);
  hipLaunchKernelGGL(recurrent_k, dim3(256), dim3(1024), 0, stream, cur2a, WrT, sru, scales, betar, thr);
  hipLaunchKernelGGL(gemm_spk_k, dim3(1, 512), dim3(256), 0, stream, sru, W3i8, cur3, OUT_);
  hipLaunchKernelGGL(scan3_k, dim3((B_ * OUT_) / 256), dim3(256), 0, stream, cur3, (float*)d_out, scales, beta2, th2);
}

// Round 6
// 1035.203 us; speedup vs baseline: 1.0459x; 1.0459x over previous
//
#include <hip/hip_runtime.h>

#define B_   256
#define NIN_ 512
#define T_   256
#define H1_  512
#define H2_  512
#define OUT_ 128

typedef __attribute__((ext_vector_type(4))) int i32x4;
typedef __attribute__((address_space(1))) const unsigned int* gl_cu;
typedef __attribute__((address_space(3))) unsigned int* ls_u;

// ---------------------------------------------------------------------------
// Per-tensor absmax -> scale = max|W|/127.  One block per tensor.
// ---------------------------------------------------------------------------
__global__ void absmax_k(const float* __restrict__ W1, const float* __restrict__ W2,
                         const float* __restrict__ Wr, const float* __restrict__ W3,
                         float* __restrict__ scales) {
  const float* W; int n;
  switch (blockIdx.x) {
    case 0:  W = W1; n = H1_ * NIN_; break;
    case 1:  W = W2; n = H2_ * H1_;  break;
    case 2:  W = Wr; n = H2_ * H2_;  break;
    default: W = W3; n = OUT_ * H2_; break;
  }
  int tid = threadIdx.x;
  float m = 0.f;
  const float4* W4 = (const float4*)W;
  int n4 = n >> 2;
  for (int i = tid; i < n4; i += 256) {
    float4 v = W4[i];
    m = fmaxf(m, fmaxf(fmaxf(fabsf(v.x), fabsf(v.y)), fmaxf(fabsf(v.z), fabsf(v.w))));
  }
  __shared__ float red[256];
  red[tid] = m;
  __syncthreads();
  for (int s = 128; s > 0; s >>= 1) {
    if (tid < s) red[tid] = fmaxf(red[tid], red[tid + s]);
    __syncthreads();
  }
  if (tid == 0) scales[blockIdx.x] = red[0] / 127.0f;
}

// ---------------------------------------------------------------------------
// Fused quantization of all four weight tensors (one launch).
//  blocks 0..1023    : W1 -> fp32 q*s, transposed [NIN][H1]    (W1qT)
//  blocks 1024..2047 : W2 -> int8 q, row-major [H2][H1]        (W2i8)
//  blocks 2048..3071 : Wr -> int8 q, presyn-major [H2][H2]     (WrT, transposed)
//  blocks 3072..3327 : W3 -> int8 q, row-major [OUT][H2]       (W3i8)
// ---------------------------------------------------------------------------
__global__ void quant_all_k(const float* __restrict__ W1, const float* __restrict__ W2,
                            const float* __restrict__ Wr, const float* __restrict__ W3,
                            const float* __restrict__ scales,
                            float* __restrict__ W1qT, signed char* __restrict__ W2i8,
                            signed char* __restrict__ WrT, signed char* __restrict__ W3i8) {
  const int blk = blockIdx.x;
  if (blk < 1024) {
    int idx = blk * 256 + threadIdx.x;
    int h = idx & (H1_ - 1), i = idx >> 9;
    float s = scales[0];
    float q = rintf(W1[h * NIN_ + i] / s);
    q = fminf(fmaxf(q, -127.f), 127.f);
    W1qT[idx] = q * s;
  } else if (blk < 2048) {
    int idx = (blk - 1024) * 256 + threadIdx.x;
    float s = scales[1];
    float q = rintf(W2[idx] / s);
    q = fminf(fmaxf(q, -127.f), 127.f);
    W2i8[idx] = (signed char)q;
  } else if (blk < 3072) {
    int idx = (blk - 2048) * 256 + threadIdx.x;
    int r = idx >> 9, c = idx & (H2_ - 1);
    float s = scales[2];
    float q = rintf(Wr[idx] / s);
    q = fminf(fmaxf(q, -127.f), 127.f);
    WrT[(size_t)c * H2_ + r] = (signed char)q;
  } else {
    int idx = (blk - 3072) * 256 + threadIdx.x;
    float s = scales[3];
    float q = rintf(W3[idx] / s);
    q = fminf(fmaxf(q, -127.f), 127.f);
    W3i8[idx] = (signed char)q;
  }
}

// ---------------------------------------------------------------------------
// Phase A: cur1[t,b,h] = sum_i data[b,i,t] * W1qT[i,h].  fp32.
// ROUND-2 VERIFIED STRUCTURE: 128x128 tile, 512 threads (8 waves), 4x8/thread,
// BK=16, double-buffered LDS via global_load_lds, plain __syncthreads.
// FMA order: per output element a single accumulator over k ascending
// 0..511 -> bit-identical cur1.  GOLDEN arithmetic preserved.
// ---------------------------------------------------------------------------
__global__ __launch_bounds__(512, 6) void gemm_cur1_k(const float* __restrict__ data,
                                                      const float* __restrict__ W1qT,
                                                      float* __restrict__ cur1) {
  const int b  = blockIdx.y;
  const int t0 = (blockIdx.x >> 2) << 7;
  const int h0 = (blockIdx.x & 3) << 7;
  const int tid = threadIdx.x;

  __shared__ float As[2][16][128];   // 16 KB
  __shared__ float Bs[2][16][128];   // 16 KB

  const int ty = tid >> 4, tx = tid & 15;   // ty 0..31, tx 0..15
  const int wv = tid >> 6;                  // 0..7
  const int ln = tid & 63;

  float acc[4][8];
#pragma unroll
  for (int i = 0; i < 4; i++)
#pragma unroll
    for (int j = 0; j < 8; j++) acc[i][j] = 0.f;

  const float* dbase = data + (size_t)b * NIN_ * T_;

  auto issue = [&](int kb, int buf) {
    const int kr = (wv << 1) + (ln >> 5);
    const float* ga = dbase + (size_t)(kb + kr) * T_ + t0 + ((ln & 31) << 2);
    __builtin_amdgcn_global_load_lds((gl_cu)ga, (ls_u)&As[buf][wv << 1][0], 16, 0, 0);
    const float* gb = W1qT + (size_t)(kb + kr) * H1_ + h0 + ((ln & 31) << 2);
    __builtin_amdgcn_global_load_lds((gl_cu)gb, (ls_u)&Bs[buf][wv << 1][0], 16, 0, 0);
  };

  issue(0, 0);

  for (int p = 0; p < 32; p++) {
    const int cur = p & 1;
    __syncthreads();
    if (p < 31) issue((p + 1) << 4, cur ^ 1);
#pragma unroll
    for (int k = 0; k < 16; k++) {
      float4 A0 = *(const float4*)&As[cur][k][ty * 4];
      float4 B0 = *(const float4*)&Bs[cur][k][tx * 4];
      float4 B1 = *(const float4*)&Bs[cur][k][64 + tx * 4];
      float a[4] = {A0.x, A0.y, A0.z, A0.w};
      float w[8] = {B0.x, B0.y, B0.z, B0.w, B1.x, B1.y, B1.z, B1.w};
#pragma unroll
      for (int i = 0; i < 4; i++)
#pragma unroll
        for (int j = 0; j < 8; j++)
          acc[i][j] = fmaf(a[i], w[j], acc[i][j]);
    }
  }

#pragma unroll
  for (int i = 0; i < 4; i++) {
    int row = ty * 4 + i;
    float* op = cur1 + (size_t)(t0 + row) * (B_ * H1_) + (size_t)b * H1_ + h0;
    float4 cA = {acc[i][0], acc[i][1], acc[i][2], acc[i][3]};
    float4 cB = {acc[i][4], acc[i][5], acc[i][6], acc[i][7]};
    *(float4*)(op + tx * 4)      = cA;
    *(float4*)(op + 64 + tx * 4) = cB;
  }
}

// ---------------------------------------------------------------------------
// scan1: parallel per-neuron layer-1 LIF scan (op order unchanged).
// ROUND-0 PROVEN FORM: 1 column/thread, 512 blocks (high wave count; this
// scan is latency-bound -- round-5's 4-col/thread float4 variant cut waves
// 4x and regressed ~25-30 us).
// ---------------------------------------------------------------------------
__global__ __launch_bounds__(256) void scan1_k(const float* __restrict__ cur1,
                                               unsigned char* __restrict__ s1u,
                                               const float* __restrict__ beta1p,
                                               const float* __restrict__ th1p) {
  const int n = blockIdx.x * 256 + threadIdx.x;
  const float b1 = fminf(fmaxf(beta1p[0], 0.f), 1.f);
  const float th1 = th1p[0];
  const size_t S = (size_t)B_ * H1_;
  float m1 = 0.f;
  for (int t = 0; t < T_; t += 4) {
    float c0 = cur1[(size_t)t * S + n];
    float c1 = cur1[(size_t)(t + 1) * S + n];
    float c2 = cur1[(size_t)(t + 2) * S + n];
    float c3 = cur1[(size_t)(t + 3) * S + n];
    m1 = b1 * m1 + c0; bool s0 = m1 - th1 > 0.f; if (s0) m1 = 0.f;
    s1u[(size_t)t * S + n] = s0;
    m1 = b1 * m1 + c1; bool s1 = m1 - th1 > 0.f; if (s1) m1 = 0.f;
    s1u[(size_t)(t + 1) * S + n] = s1;
    m1 = b1 * m1 + c2; bool s2 = m1 - th1 > 0.f; if (s2) m1 = 0.f;
    s1u[(size_t)(t + 2) * S + n] = s2;
    m1 = b1 * m1 + c3; bool s3 = m1 - th1 > 0.f; if (s3) m1 = 0.f;
    s1u[(size_t)(t + 3) * S + n] = s3;
  }
}

// ---------------------------------------------------------------------------
// Spike GEMM via i8 MFMA (exact integer sums, i32 accumulate).  Numerics
// VERIFIED round 5 (absmax 0.0).  Round-6: double-buffered LDS -> ONE
// barrier per K-block instead of three, with next K-block's global loads
// issued after the barrier (hidden under MFMAs).  Hazard audit: write(i+1)
// targets buf(i-1); every wave's mfma(i-1) precedes its write(i) precedes
// sync(i), and any wave at write(i+1) passed sync(i) -> no read-clobber.
// ---------------------------------------------------------------------------
__global__ __launch_bounds__(256) void gemm_spk_k(const unsigned char* __restrict__ A8,
                                                  const signed char* __restrict__ Bw,
                                                  float* __restrict__ C, int N) {
  __shared__ __align__(16) signed char As[2][128 * 80];   // 20 KB
  __shared__ __align__(16) signed char Bs[2][128 * 80];   // 20 KB
  const int tid = threadIdx.x;
  const int m0 = blockIdx.y << 7;
  const int n0 = blockIdx.x << 7;
  const int lane = tid & 63, wave = tid >> 6;
  const int quad = lane >> 4, lm = lane & 15;
  const int wm = wave << 5;

  i32x4 acc[2][8];
#pragma unroll
  for (int s = 0; s < 2; s++)
#pragma unroll
    for (int n = 0; n < 8; n++) acc[s][n] = (i32x4){0, 0, 0, 0};

  const int row = tid >> 2;            // 0..63 (+64 on second pass)
  const int offB = (tid & 3) << 4;     // 0/16/32/48 within 64-byte k-window

  uint4 av[2], bv[2];
  auto gload = [&](int kb) {
#pragma unroll
    for (int i = 0; i < 2; i++) {
      const int r = row + (i << 6);
      av[i] = *(const uint4*)(A8 + (size_t)(m0 + r) * 512 + kb + offB);
      bv[i] = *(const uint4*)(Bw + (size_t)(n0 + r) * 512 + kb + offB);
    }
  };

  gload(0);
  int buf = 0;
  for (int kb8 = 0; kb8 < 8; kb8++) {
#pragma unroll
    for (int i = 0; i < 2; i++) {
      const int r = row + (i << 6);
      *(uint4*)&As[buf][r * 80 + offB] = av[i];
      *(uint4*)&Bs[buf][r * 80 + offB] = bv[i];
    }
    __syncthreads();
    if (kb8 < 7) gload((kb8 + 1) << 6);   // overlaps with MFMAs below
    i32x4 a0 = *(const i32x4*)&As[buf][(wm + lm) * 80 + (quad << 4)];
    i32x4 a1 = *(const i32x4*)&As[buf][(wm + 16 + lm) * 80 + (quad << 4)];
    i32x4 bq[8];
#pragma unroll
    for (int n = 0; n < 8; n++)
      bq[n] = *(const i32x4*)&Bs[buf][((n << 4) + lm) * 80 + (quad << 4)];
#pragma unroll
    for (int n = 0; n < 8; n++) {
      acc[0][n] = __builtin_amdgcn_mfma_i32_16x16x64_i8(a0, bq[n], acc[0][n], 0, 0, 0);
      acc[1][n] = __builtin_amdgcn_mfma_i32_16x16x64_i8(a1, bq[n], acc[1][n], 0, 0, 0);
    }
    buf ^= 1;
  }

#pragma unroll
  for (int s = 0; s < 2; s++)
#pragma unroll
    for (int n = 0; n < 8; n++) {
      int orow = m0 + wm + (s << 4) + quad * 4;
      int col = n0 + (n << 4) + lm;
#pragma unroll
      for (int r = 0; r < 4; r++)
        C[(size_t)(orow + r) * N + col] = (float)acc[s][n][r];
    }
}

// ---------------------------------------------------------------------------
__device__ __forceinline__ void unp_add(unsigned w, int* a) {
  int iw = (int)w;
  a[0] += (iw << 24) >> 24;
  a[1] += (iw << 16) >> 24;
  a[2] += (iw << 8) >> 24;
  a[3] += iw >> 24;
}

// ---------------------------------------------------------------------------
// Sequential recurrent layer.  One block per batch row, 1024 threads.
// ---------------------------------------------------------------------------
__global__ __launch_bounds__(1024) void recurrent_k(
    const float* __restrict__ cur2a,       // [T*B, H2]
    const signed char* __restrict__ WrT,   // [H2][H2] presyn-major
    unsigned char* __restrict__ sru,       // [T*B, H2]
    const float* __restrict__ scales,
    const float* __restrict__ betarp, const float* __restrict__ thrp) {
  const int b = blockIdx.x;
  const int tid = threadIdx.x;
  const float s2sc = scales[1];
  const float srsc = scales[2];
  const float br = fminf(fmaxf(betarp[0], 0.f), 1.f);
  const float thr = thrp[0];

  const unsigned* WrT4 = (const unsigned*)WrT;   // [H2][128] dwords

  __shared__ unsigned WrL[256 * 128];   // 128 KB: presyn rows 0..255
  __shared__ int red[8][H2_];           // 16 KB
  __shared__ int lstLo[2][256];         // 2 KB
  __shared__ int lstHi[2][256];         // 2 KB
  __shared__ int ncLo[2], ncHi[2];

  {
    const uint4* src = (const uint4*)WrT4;
    uint4* dst = (uint4*)WrL;
    for (int i = tid; i < 8192; i += 1024) dst[i] = src[i];
  }
  if (tid < 2) { ncLo[tid] = 0; ncHi[tid] = 0; }
  __syncthreads();

  float mr = 0.f, sr_own = 0.f;
  const int g = tid >> 7;        // 0..7
  const int c = tid & 127;       // dword column

  for (int t = 0; t < T_; t++) {
    const int old = t & 1, nxt = old ^ 1;
    float c2 = 0.f;
    if (tid < H2_) c2 = cur2a[((size_t)t * B_ + b) * H2_ + tid];
    if (tid == 1022) ncLo[nxt] = 0;
    if (tid == 1023) ncHi[nxt] = 0;
    const int nLo = ncLo[old];
    const int nHi = ncHi[old];
    const int* LLo = lstLo[old];
    const int* LHi = lstHi[old];

    int a4[4] = {0, 0, 0, 0};
    // ---- LDS-resident half (rows < 256) ----
    {
      int k = g;
      for (; k + 56 < nLo; k += 64) {
        int i0 = LLo[k],      i1 = LLo[k + 8],  i2 = LLo[k + 16], i3 = LLo[k + 24];
        int i4 = LLo[k + 32], i5 = LLo[k + 40], i6 = LLo[k + 48], i7 = LLo[k + 56];
        unsigned w0 = WrL[(i0 << 7) + c], w1 = WrL[(i1 << 7) + c];
        unsigned w2 = WrL[(i2 << 7) + c], w3 = WrL[(i3 << 7) + c];
        unsigned w4 = WrL[(i4 << 7) + c], w5 = WrL[(i5 << 7) + c];
        unsigned w6 = WrL[(i6 << 7) + c], w7 = WrL[(i7 << 7) + c];
        unp_add(w0, a4); unp_add(w1, a4); unp_add(w2, a4); unp_add(w3, a4);
        unp_add(w4, a4); unp_add(w5, a4); unp_add(w6, a4); unp_add(w7, a4);
      }
      for (; k + 24 < nLo; k += 32) {
        int i0 = LLo[k], i1 = LLo[k + 8], i2 = LLo[k + 16], i3 = LLo[k + 24];
        unsigned w0 = WrL[(i0 << 7) + c], w1 = WrL[(i1 << 7) + c];
        unsigned w2 = WrL[(i2 << 7) + c], w3 = WrL[(i3 << 7) + c];
        unp_add(w0, a4); unp_add(w1, a4); unp_add(w2, a4); unp_add(w3, a4);
      }
      for (; k < nLo; k += 8) unp_add(WrL[(LLo[k] << 7) + c], a4);
    }
    // ---- global half (rows >= 256) ----
    {
      int k = g;
      for (; k + 56 < nHi; k += 64) {
        int i0 = LHi[k],      i1 = LHi[k + 8],  i2 = LHi[k + 16], i3 = LHi[k + 24];
        int i4 = LHi[k + 32], i5 = LHi[k + 40], i6 = LHi[k + 48], i7 = LHi[k + 56];
        unsigned w0 = WrT4[(i0 << 7) + c], w1 = WrT4[(i1 << 7) + c];
        unsigned w2 = WrT4[(i2 << 7) + c], w3 = WrT4[(i3 << 7) + c];
        unsigned w4 = WrT4[(i4 << 7) + c], w5 = WrT4[(i5 << 7) + c];
        unsigned w6 = WrT4[(i6 << 7) + c], w7 = WrT4[(i7 << 7) + c];
        unp_add(w0, a4); unp_add(w1, a4); unp_add(w2, a4); unp_add(w3, a4);
        unp_add(w4, a4); unp_add(w5, a4); unp_add(w6, a4); unp_add(w7, a4);
      }
      for (; k + 24 < nHi; k += 32) {
        int i0 = LHi[k], i1 = LHi[k + 8], i2 = LHi[k + 16], i3 = LHi[k + 24];
        unsigned w0 = WrT4[(i0 << 7) + c], w1 = WrT4[(i1 << 7) + c];
        unsigned w2 = WrT4[(i2 << 7) + c], w3 = WrT4[(i3 << 7) + c];
        unp_add(w0, a4); unp_add(w1, a4); unp_add(w2, a4); unp_add(w3, a4);
      }
      for (; k < nHi; k += 8) unp_add(WrT4[(LHi[k] << 7) + c], a4);
    }
    *(int4*)&red[g][c << 2] = make_int4(a4[0], a4[1], a4[2], a4[3]);
    __syncthreads();                               // S1

    bool spike = false;
    if (tid < H2_) {
      int acc = red[0][tid] + red[1][tid] + red[2][tid] + red[3][tid]
              + red[4][tid] + red[5][tid] + red[6][tid] + red[7][tid];
      float h = s2sc * c2 + srsc * (float)acc;
      mr = (br * mr + h) * (1.f - sr_own);
      sr_own = (mr - thr > 0.f) ? 1.f : 0.f;
      sru[((size_t)t * B_ + b) * H2_ + tid] = (unsigned char)(sr_own != 0.f);
      spike = (sr_own != 0.f);
    }
    unsigned long long bm = __ballot(spike);
    if (bm != 0ull) {
      const int lane = tid & 63;
      const int ldr = (int)__ffsll((long long)bm) - 1;
      int* cnt = (tid < 256) ? &ncLo[nxt] : &ncHi[nxt];   // wave-uniform choice
      int* dst = (tid < 256) ? lstLo[nxt] : lstHi[nxt];
      int base = 0;
      if (lane == ldr) base = atomicAdd(cnt, (int)__popcll(bm));
      base = __shfl(base, ldr);
      if (spike)
        dst[base + (int)__popcll(bm & ((1ull << lane) - 1ull))] = tid;
    }
    __syncthreads();                               // S2
  }
}

// ---------------------------------------------------------------------------
// scan3: parallel layer-2 LIF scan over precomputed cur3 sums.
// ---------------------------------------------------------------------------
__global__ __launch_bounds__(256) void scan3_k(const float* __restrict__ cur3,
                                               float* __restrict__ out,
                                               const float* __restrict__ scales,
                                               const float* __restrict__ beta2p,
                                               const float* __restrict__ th2p) {
  const int n = blockIdx.x * 256 + threadIdx.x;
  const float s3sc = scales[3];
  const float b2 = fminf(fmaxf(beta2p[0], 0.f), 1.f);
  const float th2 = th2p[0];
  const size_t S = (size_t)B_ * OUT_;
  float m2 = 0.f;
  for (int t = 0; t < T_; t += 4) {
    float v0 = cur3[(size_t)t * S + n];
    float v1 = cur3[(size_t)(t + 1) * S + n];
    float v2 = cur3[(size_t)(t + 2) * S + n];
    float v3 = cur3[(size_t)(t + 3) * S + n];
    m2 = b2 * m2 + s3sc * v0; float p0 = (m2 - th2 > 0.f) ? 1.f : 0.f; m2 *= (1.f - p0);
    out[(size_t)t * S + n] = p0;
    m2 = b2 * m2 + s3sc * v1; float p1 = (m2 - th2 > 0.f) ? 1.f : 0.f; m2 *= (1.f - p1);
    out[(size_t)(t + 1) * S + n] = p1;
    m2 = b2 * m2 + s3sc * v2; float p2 = (m2 - th2 > 0.f) ? 1.f : 0.f; m2 *= (1.f - p2);
    out[(size_t)(t + 2) * S + n] = p2;
    m2 = b2 * m2 + s3sc * v3; float p3 = (m2 - th2 > 0.f) ? 1.f : 0.f; m2 *= (1.f - p3);
    out[(size_t)(t + 3) * S + n] = p3;
  }
}

// ---------------------------------------------------------------------------
extern "C" void kernel_launch(void* const* d_in, const int* in_sizes, int n_in,
                              void* d_out, int out_size, void* d_ws, size_t ws_size,
                              hipStream_t stream) {
  const float* data  = (const float*)d_in[0];
  const float* W1    = (const float*)d_in[1];
  const float* W2    = (const float*)d_in[2];
  const float* Wr    = (const float*)d_in[3];
  const float* W3    = (const float*)d_in[4];
  const float* beta1 = (const float*)d_in[5];
  const float* th1   = (const float*)d_in[6];
  const float* betar = (const float*)d_in[7];
  const float* thr   = (const float*)d_in[8];
  const float* beta2 = (const float*)d_in[9];
  const float* th2   = (const float*)d_in[10];

  char* ws = (char*)d_ws;
  float*         scales = (float*)ws;                                   // @0
  float*         W1qT   = (float*)(ws + 4096);                          // 1 MB [NIN][H1]
  signed char*   W2i8   = (signed char*)(ws + 4096 + 1048576);          // 256 KB [H2][H1]
  signed char*   W3i8   = (signed char*)(ws + 4096 + 1048576 + 524288); // 64 KB [OUT][H2]
  signed char*   WrT    = (signed char*)(ws + 4096 + 1048576 + 524288 + 131072); // 256 KB
  // region A (128 MB): cur1 -> cur2a -> cur3 (sequential lifetimes)
  float*         regA   = (float*)(ws + (size_t)4194304);
  // region B (64 MB): s1u + sru
  unsigned char* regB   = (unsigned char*)(ws + (size_t)4194304 + 134217728);

  float* cur1  = regA;
  float* cur2a = regA;
  float* cur3  = regA;
  unsigned char* s1u = regB;
  unsigned char* sru = regB + (size_t)33554432;

  hipLaunchKernelGGL(absmax_k, dim3(4), dim3(256), 0, stream, W1, W2, Wr, W3, scales);
  hipLaunchKernelGGL(quant_all_k, dim3(3328), dim3(256), 0, stream,
                     W1, W2, Wr, W3, scales, W1qT, W2i8, WrT, W3i8);

  hipLaunchKernelGGL(gemm_cur1_k, dim3(8, 256), dim3(512), 0, stream, data, W1qT, cur1);
  hipLaunchKernelGGL(scan1_k, dim3((B_ * H1_) / 256), dim3(256), 0, stream, cur1, s1u, beta1, th1);
  hipLaunchKernelGGL(gemm_spk_k, dim3(4, 512), dim3(256), 0, stream, s1u, W2i8, cur2a, H2_);
  hipLaunchKernelGGL(recurrent_k, dim3(256), dim3(1024), 0, stream, cur2a, WrT, sru, scales, betar, thr);
  hipLaunchKernelGGL(gemm_spk_k, dim3(1, 512), dim3(256), 0, stream, sru, W3i8, cur3, OUT_);
  hipLaunchKernelGGL(scan3_k, dim3((B_ * OUT_) / 256), dim3(256), 0, stream, cur3, (float*)d_out, scales, beta2, th2);
}

// Round 7
// 984.960 us; speedup vs baseline: 1.0993x; 1.0510x over previous
//
#include <hip/hip_runtime.h>

#define B_   256
#define NIN_ 512
#define T_   256
#define H1_  512
#define H2_  512
#define OUT_ 128

typedef __attribute__((ext_vector_type(4))) int i32x4;
typedef __attribute__((address_space(1))) const unsigned int* gl_cu;
typedef __attribute__((address_space(3))) unsigned int* ls_u;

// ---------------------------------------------------------------------------
// Per-tensor absmax, parallel: 64 blocks per tensor, atomicMax on uint bits
// (valid: all values are fabs() >= 0, and IEEE non-negative floats order
// identically to their uint bit patterns).  smax[] zeroed by host-side
// hipMemsetAsync before launch.  Max is order-independent -> identical scale.
// ---------------------------------------------------------------------------
__global__ __launch_bounds__(256) void absmax_k(const float* __restrict__ W1,
                                                const float* __restrict__ W2,
                                                const float* __restrict__ Wr,
                                                const float* __restrict__ W3,
                                                unsigned* __restrict__ smax) {
  const int tens = blockIdx.x >> 6;   // 0..3
  const int sub  = blockIdx.x & 63;
  const float* W; int n4;
  switch (tens) {
    case 0:  W = W1; n4 = (H1_ * NIN_) >> 2; break;
    case 1:  W = W2; n4 = (H2_ * H1_) >> 2;  break;
    case 2:  W = Wr; n4 = (H2_ * H2_) >> 2;  break;
    default: W = W3; n4 = (OUT_ * H2_) >> 2; break;
  }
  const int per = n4 >> 6;            // 1024 (W1/W2/Wr) or 256 (W3)
  const float4* W4 = (const float4*)W + sub * per;
  int tid = threadIdx.x;
  float m = 0.f;
  for (int i = tid; i < per; i += 256) {
    float4 v = W4[i];
    m = fmaxf(m, fmaxf(fmaxf(fabsf(v.x), fabsf(v.y)), fmaxf(fabsf(v.z), fabsf(v.w))));
  }
  __shared__ float red[256];
  red[tid] = m;
  __syncthreads();
  for (int s = 128; s > 0; s >>= 1) {
    if (tid < s) red[tid] = fmaxf(red[tid], red[tid + s]);
    __syncthreads();
  }
  if (tid == 0) atomicMax(smax + tens, __float_as_uint(red[0]));
}

// ---------------------------------------------------------------------------
// Fused quantization of all four weight tensors (one launch).
//  blocks 0..1023    : W1 -> fp32 q*s, transposed [NIN][H1]    (W1qT)
//  blocks 1024..2047 : W2 -> int8 q, row-major [H2][H1]        (W2i8)
//  blocks 2048..3071 : Wr -> int8 q, presyn-major [H2][H2]     (WrT, transposed)
//  blocks 3072..3327 : W3 -> int8 q, row-major [OUT][H2]       (W3i8)
// Scales derived inline from smax bits (s = max/127, bit-identical to the
// old scales[] values); block 0 also publishes scales[] for recurrent/scan3.
// ---------------------------------------------------------------------------
__global__ void quant_all_k(const float* __restrict__ W1, const float* __restrict__ W2,
                            const float* __restrict__ Wr, const float* __restrict__ W3,
                            const unsigned* __restrict__ smax,
                            float* __restrict__ scales,
                            float* __restrict__ W1qT, signed char* __restrict__ W2i8,
                            signed char* __restrict__ WrT, signed char* __restrict__ W3i8) {
  const int blk = blockIdx.x;
  if (blk == 0 && threadIdx.x < 4)
    scales[threadIdx.x] = __uint_as_float(smax[threadIdx.x]) / 127.0f;
  if (blk < 1024) {
    int idx = blk * 256 + threadIdx.x;
    int h = idx & (H1_ - 1), i = idx >> 9;
    float s = __uint_as_float(smax[0]) / 127.0f;
    float q = rintf(W1[h * NIN_ + i] / s);
    q = fminf(fmaxf(q, -127.f), 127.f);
    W1qT[idx] = q * s;
  } else if (blk < 2048) {
    int idx = (blk - 1024) * 256 + threadIdx.x;
    float s = __uint_as_float(smax[1]) / 127.0f;
    float q = rintf(W2[idx] / s);
    q = fminf(fmaxf(q, -127.f), 127.f);
    W2i8[idx] = (signed char)q;
  } else if (blk < 3072) {
    int idx = (blk - 2048) * 256 + threadIdx.x;
    int r = idx >> 9, c = idx & (H2_ - 1);
    float s = __uint_as_float(smax[2]) / 127.0f;
    float q = rintf(Wr[idx] / s);
    q = fminf(fmaxf(q, -127.f), 127.f);
    WrT[(size_t)c * H2_ + r] = (signed char)q;
  } else {
    int idx = (blk - 3072) * 256 + threadIdx.x;
    float s = __uint_as_float(smax[3]) / 127.0f;
    float q = rintf(W3[idx] / s);
    q = fminf(fmaxf(q, -127.f), 127.f);
    W3i8[idx] = (signed char)q;
  }
}

// ---------------------------------------------------------------------------
// Phase A: cur1[t,b,h] = sum_i data[b,i,t] * W1qT[i,h].  fp32.
// ROUND-2 VERIFIED STRUCTURE: 128x128 tile, 512 threads (8 waves), 4x8/thread,
// BK=16, double-buffered LDS via global_load_lds, plain __syncthreads.
// FMA order: per output element a single accumulator over k ascending
// 0..511 -> bit-identical cur1.  GOLDEN arithmetic preserved.  PARKED at
// ~385 us (56% fp32 peak): rounds 1/3/4 structural variants all regressed.
// ---------------------------------------------------------------------------
__global__ __launch_bounds__(512, 6) void gemm_cur1_k(const float* __restrict__ data,
                                                      const float* __restrict__ W1qT,
                                                      float* __restrict__ cur1) {
  const int b  = blockIdx.y;
  const int t0 = (blockIdx.x >> 2) << 7;
  const int h0 = (blockIdx.x & 3) << 7;
  const int tid = threadIdx.x;

  __shared__ float As[2][16][128];   // 16 KB
  __shared__ float Bs[2][16][128];   // 16 KB

  const int ty = tid >> 4, tx = tid & 15;   // ty 0..31, tx 0..15
  const int wv = tid >> 6;                  // 0..7
  const int ln = tid & 63;

  float acc[4][8];
#pragma unroll
  for (int i = 0; i < 4; i++)
#pragma unroll
    for (int j = 0; j < 8; j++) acc[i][j] = 0.f;

  const float* dbase = data + (size_t)b * NIN_ * T_;

  auto issue = [&](int kb, int buf) {
    const int kr = (wv << 1) + (ln >> 5);
    const float* ga = dbase + (size_t)(kb + kr) * T_ + t0 + ((ln & 31) << 2);
    __builtin_amdgcn_global_load_lds((gl_cu)ga, (ls_u)&As[buf][wv << 1][0], 16, 0, 0);
    const float* gb = W1qT + (size_t)(kb + kr) * H1_ + h0 + ((ln & 31) << 2);
    __builtin_amdgcn_global_load_lds((gl_cu)gb, (ls_u)&Bs[buf][wv << 1][0], 16, 0, 0);
  };

  issue(0, 0);

  for (int p = 0; p < 32; p++) {
    const int cur = p & 1;
    __syncthreads();
    if (p < 31) issue((p + 1) << 4, cur ^ 1);
#pragma unroll
    for (int k = 0; k < 16; k++) {
      float4 A0 = *(const float4*)&As[cur][k][ty * 4];
      float4 B0 = *(const float4*)&Bs[cur][k][tx * 4];
      float4 B1 = *(const float4*)&Bs[cur][k][64 + tx * 4];
      float a[4] = {A0.x, A0.y, A0.z, A0.w};
      float w[8] = {B0.x, B0.y, B0.z, B0.w, B1.x, B1.y, B1.z, B1.w};
#pragma unroll
      for (int i = 0; i < 4; i++)
#pragma unroll
        for (int j = 0; j < 8; j++)
          acc[i][j] = fmaf(a[i], w[j], acc[i][j]);
    }
  }

#pragma unroll
  for (int i = 0; i < 4; i++) {
    int row = ty * 4 + i;
    float* op = cur1 + (size_t)(t0 + row) * (B_ * H1_) + (size_t)b * H1_ + h0;
    float4 cA = {acc[i][0], acc[i][1], acc[i][2], acc[i][3]};
    float4 cB = {acc[i][4], acc[i][5], acc[i][6], acc[i][7]};
    *(float4*)(op + tx * 4)      = cA;
    *(float4*)(op + 64 + tx * 4) = cB;
  }
}

// ---------------------------------------------------------------------------
// scan1: parallel per-neuron layer-1 LIF scan (op order unchanged).
// Latency-bound (round-5 evidence: wave count is the sensitive resource).
// Round-7: unroll 8 -> 8 independent loads in flight per wave (2x in-flight
// bytes), same 512-block/1-col-per-thread shape, identical per-column chain.
// ---------------------------------------------------------------------------
__global__ __launch_bounds__(256) void scan1_k(const float* __restrict__ cur1,
                                               unsigned char* __restrict__ s1u,
                                               const float* __restrict__ beta1p,
                                               const float* __restrict__ th1p) {
  const int n = blockIdx.x * 256 + threadIdx.x;
  const float b1 = fminf(fmaxf(beta1p[0], 0.f), 1.f);
  const float th1 = th1p[0];
  const size_t S = (size_t)B_ * H1_;
  float m1 = 0.f;
  for (int t = 0; t < T_; t += 8) {
    float c[8];
#pragma unroll
    for (int j = 0; j < 8; j++) c[j] = cur1[(size_t)(t + j) * S + n];
#pragma unroll
    for (int j = 0; j < 8; j++) {
      m1 = b1 * m1 + c[j];
      bool s = m1 - th1 > 0.f;
      if (s) m1 = 0.f;
      s1u[(size_t)(t + j) * S + n] = s;
    }
  }
}

// ---------------------------------------------------------------------------
// Spike GEMM via i8 MFMA (exact integer sums, i32 accumulate).  Numerics
// VERIFIED (absmax 0.0).  Double-buffered LDS, ONE barrier per K-block,
// next K-block's global loads issued post-barrier (hidden under MFMAs).
// Round-7: m-tile on blockIdx.x (fastest) so the blocks sharing an A-row
// panel sit 512 apart -> same XCD -> A served from local L2.
// ---------------------------------------------------------------------------
__global__ __launch_bounds__(256) void gemm_spk_k(const unsigned char* __restrict__ A8,
                                                  const signed char* __restrict__ Bw,
                                                  float* __restrict__ C, int N) {
  __shared__ __align__(16) signed char As[2][128 * 80];   // 20 KB
  __shared__ __align__(16) signed char Bs[2][128 * 80];   // 20 KB
  const int tid = threadIdx.x;
  const int m0 = blockIdx.x << 7;
  const int n0 = blockIdx.y << 7;
  const int lane = tid & 63, wave = tid >> 6;
  const int quad = lane >> 4, lm = lane & 15;
  const int wm = wave << 5;

  i32x4 acc[2][8];
#pragma unroll
  for (int s = 0; s < 2; s++)
#pragma unroll
    for (int n = 0; n < 8; n++) acc[s][n] = (i32x4){0, 0, 0, 0};

  const int row = tid >> 2;            // 0..63 (+64 on second pass)
  const int offB = (tid & 3) << 4;     // 0/16/32/48 within 64-byte k-window

  uint4 av[2], bv[2];
  auto gload = [&](int kb) {
#pragma unroll
    for (int i = 0; i < 2; i++) {
      const int r = row + (i << 6);
      av[i] = *(const uint4*)(A8 + (size_t)(m0 + r) * 512 + kb + offB);
      bv[i] = *(const uint4*)(Bw + (size_t)(n0 + r) * 512 + kb + offB);
    }
  };

  gload(0);
  int buf = 0;
  for (int kb8 = 0; kb8 < 8; kb8++) {
#pragma unroll
    for (int i = 0; i < 2; i++) {
      const int r = row + (i << 6);
      *(uint4*)&As[buf][r * 80 + offB] = av[i];
      *(uint4*)&Bs[buf][r * 80 + offB] = bv[i];
    }
    __syncthreads();
    if (kb8 < 7) gload((kb8 + 1) << 6);   // overlaps with MFMAs below
    i32x4 a0 = *(const i32x4*)&As[buf][(wm + lm) * 80 + (quad << 4)];
    i32x4 a1 = *(const i32x4*)&As[buf][(wm + 16 + lm) * 80 + (quad << 4)];
    i32x4 bq[8];
#pragma unroll
    for (int n = 0; n < 8; n++)
      bq[n] = *(const i32x4*)&Bs[buf][((n << 4) + lm) * 80 + (quad << 4)];
#pragma unroll
    for (int n = 0; n < 8; n++) {
      acc[0][n] = __builtin_amdgcn_mfma_i32_16x16x64_i8(a0, bq[n], acc[0][n], 0, 0, 0);
      acc[1][n] = __builtin_amdgcn_mfma_i32_16x16x64_i8(a1, bq[n], acc[1][n], 0, 0, 0);
    }
    buf ^= 1;
  }

#pragma unroll
  for (int s = 0; s < 2; s++)
#pragma unroll
    for (int n = 0; n < 8; n++) {
      int orow = m0 + wm + (s << 4) + quad * 4;
      int col = n0 + (n << 4) + lm;
#pragma unroll
      for (int r = 0; r < 4; r++)
        C[(size_t)(orow + r) * N + col] = (float)acc[s][n][r];
    }
}

// ---------------------------------------------------------------------------
__device__ __forceinline__ void unp_add(unsigned w, int* a) {
  int iw = (int)w;
  a[0] += (iw << 24) >> 24;
  a[1] += (iw << 16) >> 24;
  a[2] += (iw << 8) >> 24;
  a[3] += iw >> 24;
}

// ---------------------------------------------------------------------------
// Sequential recurrent layer.  One block per batch row, 1024 threads.
// ---------------------------------------------------------------------------
__global__ __launch_bounds__(1024) void recurrent_k(
    const float* __restrict__ cur2a,       // [T*B, H2]
    const signed char* __restrict__ WrT,   // [H2][H2] presyn-major
    unsigned char* __restrict__ sru,       // [T*B, H2]
    const float* __restrict__ scales,
    const float* __restrict__ betarp, const float* __restrict__ thrp) {
  const int b = blockIdx.x;
  const int tid = threadIdx.x;
  const float s2sc = scales[1];
  const float srsc = scales[2];
  const float br = fminf(fmaxf(betarp[0], 0.f), 1.f);
  const float thr = thrp[0];

  const unsigned* WrT4 = (const unsigned*)WrT;   // [H2][128] dwords

  __shared__ unsigned WrL[256 * 128];   // 128 KB: presyn rows 0..255
  __shared__ int red[8][H2_];           // 16 KB
  __shared__ int lstLo[2][256];         // 2 KB
  __shared__ int lstHi[2][256];         // 2 KB
  __shared__ int ncLo[2], ncHi[2];

  {
    const uint4* src = (const uint4*)WrT4;
    uint4* dst = (uint4*)WrL;
    for (int i = tid; i < 8192; i += 1024) dst[i] = src[i];
  }
  if (tid < 2) { ncLo[tid] = 0; ncHi[tid] = 0; }
  __syncthreads();

  float mr = 0.f, sr_own = 0.f;
  const int g = tid >> 7;        // 0..7
  const int c = tid & 127;       // dword column

  for (int t = 0; t < T_; t++) {
    const int old = t & 1, nxt = old ^ 1;
    float c2 = 0.f;
    if (tid < H2_) c2 = cur2a[((size_t)t * B_ + b) * H2_ + tid];
    if (tid == 1022) ncLo[nxt] = 0;
    if (tid == 1023) ncHi[nxt] = 0;
    const int nLo = ncLo[old];
    const int nHi = ncHi[old];
    const int* LLo = lstLo[old];
    const int* LHi = lstHi[old];

    int a4[4] = {0, 0, 0, 0};
    // ---- LDS-resident half (rows < 256) ----
    {
      int k = g;
      for (; k + 56 < nLo; k += 64) {
        int i0 = LLo[k],      i1 = LLo[k + 8],  i2 = LLo[k + 16], i3 = LLo[k + 24];
        int i4 = LLo[k + 32], i5 = LLo[k + 40], i6 = LLo[k + 48], i7 = LLo[k + 56];
        unsigned w0 = WrL[(i0 << 7) + c], w1 = WrL[(i1 << 7) + c];
        unsigned w2 = WrL[(i2 << 7) + c], w3 = WrL[(i3 << 7) + c];
        unsigned w4 = WrL[(i4 << 7) + c], w5 = WrL[(i5 << 7) + c];
        unsigned w6 = WrL[(i6 << 7) + c], w7 = WrL[(i7 << 7) + c];
        unp_add(w0, a4); unp_add(w1, a4); unp_add(w2, a4); unp_add(w3, a4);
        unp_add(w4, a4); unp_add(w5, a4); unp_add(w6, a4); unp_add(w7, a4);
      }
      for (; k + 24 < nLo; k += 32) {
        int i0 = LLo[k], i1 = LLo[k + 8], i2 = LLo[k + 16], i3 = LLo[k + 24];
        unsigned w0 = WrL[(i0 << 7) + c], w1 = WrL[(i1 << 7) + c];
        unsigned w2 = WrL[(i2 << 7) + c], w3 = WrL[(i3 << 7) + c];
        unp_add(w0, a4); unp_add(w1, a4); unp_add(w2, a4); unp_add(w3, a4);
      }
      for (; k < nLo; k += 8) unp_add(WrL[(LLo[k] << 7) + c], a4);
    }
    // ---- global half (rows >= 256) ----
    {
      int k = g;
      for (; k + 56 < nHi; k += 64) {
        int i0 = LHi[k],      i1 = LHi[k + 8],  i2 = LHi[k + 16], i3 = LHi[k + 24];
        int i4 = LHi[k + 32], i5 = LHi[k + 40], i6 = LHi[k + 48], i7 = LHi[k + 56];
        unsigned w0 = WrT4[(i0 << 7) + c], w1 = WrT4[(i1 << 7) + c];
        unsigned w2 = WrT4[(i2 << 7) + c], w3 = WrT4[(i3 << 7) + c];
        unsigned w4 = WrT4[(i4 << 7) + c], w5 = WrT4[(i5 << 7) + c];
        unsigned w6 = WrT4[(i6 << 7) + c], w7 = WrT4[(i7 << 7) + c];
        unp_add(w0, a4); unp_add(w1, a4); unp_add(w2, a4); unp_add(w3, a4);
        unp_add(w4, a4); unp_add(w5, a4); unp_add(w6, a4); unp_add(w7, a4);
      }
      for (; k + 24 < nHi; k += 32) {
        int i0 = LHi[k], i1 = LHi[k + 8], i2 = LHi[k + 16], i3 = LHi[k + 24];
        unsigned w0 = WrT4[(i0 << 7) + c], w1 = WrT4[(i1 << 7) + c];
        unsigned w2 = WrT4[(i2 << 7) + c], w3 = WrT4[(i3 << 7) + c];
        unp_add(w0, a4); unp_add(w1, a4); unp_add(w2, a4); unp_add(w3, a4);
      }
      for (; k < nHi; k += 8) unp_add(WrT4[(LHi[k] << 7) + c], a4);
    }
    *(int4*)&red[g][c << 2] = make_int4(a4[0], a4[1], a4[2], a4[3]);
    __syncthreads();                               // S1

    bool spike = false;
    if (tid < H2_) {
      int acc = red[0][tid] + red[1][tid] + red[2][tid] + red[3][tid]
              + red[4][tid] + red[5][tid] + red[6][tid] + red[7][tid];
      float h = s2sc * c2 + srsc * (float)acc;
      mr = (br * mr + h) * (1.f - sr_own);
      sr_own = (mr - thr > 0.f) ? 1.f : 0.f;
      sru[((size_t)t * B_ + b) * H2_ + tid] = (unsigned char)(sr_own != 0.f);
      spike = (sr_own != 0.f);
    }
    unsigned long long bm = __ballot(spike);
    if (bm != 0ull) {
      const int lane = tid & 63;
      const int ldr = (int)__ffsll((long long)bm) - 1;
      int* cnt = (tid < 256) ? &ncLo[nxt] : &ncHi[nxt];   // wave-uniform choice
      int* dst = (tid < 256) ? lstLo[nxt] : lstHi[nxt];
      int base = 0;
      if (lane == ldr) base = atomicAdd(cnt, (int)__popcll(bm));
      base = __shfl(base, ldr);
      if (spike)
        dst[base + (int)__popcll(bm & ((1ull << lane) - 1ull))] = tid;
    }
    __syncthreads();                               // S2
  }
}

// ---------------------------------------------------------------------------
// scan3: parallel layer-2 LIF scan (op order unchanged), unroll 8.
// ---------------------------------------------------------------------------
__global__ __launch_bounds__(256) void scan3_k(const float* __restrict__ cur3,
                                               float* __restrict__ out,
                                               const float* __restrict__ scales,
                                               const float* __restrict__ beta2p,
                                               const float* __restrict__ th2p) {
  const int n = blockIdx.x * 256 + threadIdx.x;
  const float s3sc = scales[3];
  const float b2 = fminf(fmaxf(beta2p[0], 0.f), 1.f);
  const float th2 = th2p[0];
  const size_t S = (size_t)B_ * OUT_;
  float m2 = 0.f;
  for (int t = 0; t < T_; t += 8) {
    float v[8];
#pragma unroll
    for (int j = 0; j < 8; j++) v[j] = cur3[(size_t)(t + j) * S + n];
#pragma unroll
    for (int j = 0; j < 8; j++) {
      m2 = b2 * m2 + s3sc * v[j];
      float p = (m2 - th2 > 0.f) ? 1.f : 0.f;
      m2 *= (1.f - p);
      out[(size_t)(t + j) * S + n] = p;
    }
  }
}

// ---------------------------------------------------------------------------
extern "C" void kernel_launch(void* const* d_in, const int* in_sizes, int n_in,
                              void* d_out, int out_size, void* d_ws, size_t ws_size,
                              hipStream_t stream) {
  const float* data  = (const float*)d_in[0];
  const float* W1    = (const float*)d_in[1];
  const float* W2    = (const float*)d_in[2];
  const float* Wr    = (const float*)d_in[3];
  const float* W3    = (const float*)d_in[4];
  const float* beta1 = (const float*)d_in[5];
  const float* th1   = (const float*)d_in[6];
  const float* betar = (const float*)d_in[7];
  const float* thr   = (const float*)d_in[8];
  const float* beta2 = (const float*)d_in[9];
  const float* th2   = (const float*)d_in[10];

  char* ws = (char*)d_ws;
  float*         scales = (float*)ws;                                   // @0 (16 B)
  unsigned*      smax   = (unsigned*)(ws + 64);                         // @64 (16 B)
  float*         W1qT   = (float*)(ws + 4096);                          // 1 MB [NIN][H1]
  signed char*   W2i8   = (signed char*)(ws + 4096 + 1048576);          // 256 KB [H2][H1]
  signed char*   W3i8   = (signed char*)(ws + 4096 + 1048576 + 524288); // 64 KB [OUT][H2]
  signed char*   WrT    = (signed char*)(ws + 4096 + 1048576 + 524288 + 131072); // 256 KB
  // region A (128 MB): cur1 -> cur2a -> cur3 (sequential lifetimes)
  float*         regA   = (float*)(ws + (size_t)4194304);
  // region B (64 MB): s1u + sru
  unsigned char* regB   = (unsigned char*)(ws + (size_t)4194304 + 134217728);

  float* cur1  = regA;
  float* cur2a = regA;
  float* cur3  = regA;
  unsigned char* s1u = regB;
  unsigned char* sru = regB + (size_t)33554432;

  hipMemsetAsync(smax, 0, 16, stream);
  hipLaunchKernelGGL(absmax_k, dim3(256), dim3(256), 0, stream, W1, W2, Wr, W3, smax);
  hipLaunchKernelGGL(quant_all_k, dim3(3328), dim3(256), 0, stream,
                     W1, W2, Wr, W3, smax, scales, W1qT, W2i8, WrT, W3i8);

  hipLaunchKernelGGL(gemm_cur1_k, dim3(8, 256), dim3(512), 0, stream, data, W1qT, cur1);
  hipLaunchKernelGGL(scan1_k, dim3((B_ * H1_) / 256), dim3(256), 0, stream, cur1, s1u, beta1, th1);
  hipLaunchKernelGGL(gemm_spk_k, dim3(512, 4), dim3(256), 0, stream, s1u, W2i8, cur2a, H2_);
  hipLaunchKernelGGL(recurrent_k, dim3(256), dim3(1024), 0, stream, cur2a, WrT, sru, scales, betar, thr);
  hipLaunchKernelGGL(gemm_spk_k, dim3(512, 1), dim3(256), 0, stream, sru, W3i8, cur3, OUT_);
  hipLaunchKernelGGL(scan3_k, dim3((B_ * OUT_) / 256), dim3(256), 0, stream, cur3, (float*)d_out, scales, beta2, th2);
}